// Round 1
// baseline (2591.131 us; speedup 1.0000x reference)
//
#include <hip/hip_runtime.h>
#include <stdint.h>

#define N_ANCH 12288
#define FM_W 128
#define NCLS 64
#define CHUNK 2048
#define NCHUNK 6
#define CWORDS 32
#define TOTWORDS 192

typedef unsigned long long u64;
typedef unsigned int u32;

// IoU > 0.5 predicate, replicating numpy op order/rounding exactly (no FMA contraction).
__device__ __forceinline__ bool iou_gt(float4 a, float fa, float4 b, float fb) {
    float xx1 = fmaxf(a.x, b.x);
    float yy1 = fmaxf(a.y, b.y);
    float xx2 = fminf(a.z, b.z);
    float yy2 = fminf(a.w, b.w);
    float dx = fmaxf(__fsub_rn(xx2, xx1), 0.0f);
    float dy = fmaxf(__fsub_rn(yy2, yy1), 0.0f);
    float inter = __fmul_rn(dx, dy);
    float denom = __fadd_rn(__fsub_rn(__fadd_rn(fa, fb), inter), 1e-9f);
    float iou = __fdiv_rn(inter, denom);
    return iou > 0.5f;
}

// ---------------- decode: boxes, score, sortable key, area ----------------
__global__ void decode_kernel(const float4* __restrict__ loc, const float* __restrict__ cls,
                              float4* __restrict__ boxes, float* __restrict__ score,
                              u32* __restrict__ key, float* __restrict__ area) {
    int i = blockIdx.x * 256 + threadIdx.x;
    if (i >= N_ANCH) return;
    float4 l = loc[i];
    int y = i >> 7;        // FM_W = 128
    int x = i & 127;
    float cx = (x + 0.5f) * 8.0f;   // exact
    float cy = (y + 0.5f) * 8.0f;   // exact
    float px = __fadd_rn(__fmul_rn(l.x, 32.0f), cx);
    float py = __fadd_rn(__fmul_rn(l.y, 32.0f), cy);
    float pw = __fmul_rn(expf(l.z), 32.0f);
    float ph = __fmul_rn(expf(l.w), 32.0f);
    float hx = __fmul_rn(pw, 0.5f);  // == wh/2 exactly
    float hy = __fmul_rn(ph, 0.5f);
    float x1 = __fsub_rn(px, hx), y1 = __fsub_rn(py, hy);
    float x2 = __fadd_rn(px, hx), y2 = __fadd_rn(py, hy);
    float4 b; b.x = x1; b.y = y1; b.z = x2; b.w = y2;
    boxes[i] = b;
    area[i] = __fmul_rn(__fsub_rn(x2, x1), __fsub_rn(y2, y1));

    const float4* cr = (const float4*)(cls + (size_t)i * NCLS);
    float mx = -INFINITY;
#pragma unroll
    for (int k = 0; k < 16; ++k) {
        float4 v = cr[k];
        mx = fmaxf(mx, fmaxf(fmaxf(v.x, v.y), fmaxf(v.z, v.w)));
    }
    // sigmoid(max) == max(sigmoid) (monotone). jax.nn.sigmoid-style stable form.
    float s;
    if (mx >= 0.0f) {
        float e = expf(-mx);
        s = __fdiv_rn(1.0f, __fadd_rn(1.0f, e));
    } else {
        float e = expf(mx);
        s = __fdiv_rn(e, __fadd_rn(1.0f, e));
    }
    score[i] = s;
    float se = (s > 0.5f) ? s : -INFINITY;   // score_eff
    u32 u = __float_as_uint(se);
    u = (u & 0x80000000u) ? ~u : (u | 0x80000000u);   // ascending-ordered uint
    key[i] = u;
}

// ---------------- rank sort: stable descending argsort via O(N^2) rank ----------------
__global__ void rank_kernel(const u32* __restrict__ key, const float4* __restrict__ boxes,
                            const float* __restrict__ area, const float* __restrict__ score,
                            int* __restrict__ rank, float4* __restrict__ sboxes,
                            float* __restrict__ sarea, u64* __restrict__ valid_words) {
    __shared__ u32 skey[N_ANCH];
    int tid = threadIdx.x;
    for (int k = tid; k < N_ANCH; k += 256) skey[k] = key[k];
    __syncthreads();
    int row = blockIdx.x * 32 + (tid >> 3);
    int part = tid & 7;
    u32 ki = skey[row];
    int r = 0;
    for (int j = part; j < N_ANCH; j += 8) {
        u32 kj = skey[j];
        r += (int)((kj > ki) || (kj == ki && j < row));
    }
    r += __shfl_xor(r, 1);
    r += __shfl_xor(r, 2);
    r += __shfl_xor(r, 4);
    if (part == 0) {
        rank[row] = r;
        sboxes[r] = boxes[row];
        sarea[r] = area[row];
        if (score[row] > 0.5f) atomicOr(&valid_words[r >> 6], 1ull << (r & 63));
    }
}

// ---------------- per-chunk diagonal suppression mask ----------------
__global__ void diag_kernel(const float4* __restrict__ sboxes, const float* __restrict__ sarea,
                            u64* __restrict__ diag) {
    int i = blockIdx.x;              // global sorted row index
    int c = i >> 11;                 // chunk of 2048
    int lane = threadIdx.x & 63;
    int wave = threadIdx.x >> 6;     // 0..3
    float4 bi = sboxes[i];
    float ai = sarea[i];
    int cb = c << 11;
#pragma unroll
    for (int w8 = 0; w8 < 8; ++w8) {
        int w = wave * 8 + w8;
        int j = cb + w * 64 + lane;
        float4 bj = sboxes[j];
        float aj = sarea[j];
        bool pred = iou_gt(bi, ai, bj, aj) && (j > i);
        u64 bits = __ballot(pred);
        if (lane == 0) diag[(size_t)i * CWORDS + w] = bits;
    }
}

// ---------------- sequential greedy scan within one chunk (1 wave) ----------------
__global__ void scan_kernel(const u64* __restrict__ diag, const u64* __restrict__ valid_words,
                            const u64* __restrict__ removed_words, u64* __restrict__ kept_words,
                            int c) {
    __shared__ u64 state[CWORDS];
    int lane = threadIdx.x;
    if (lane < CWORDS)
        state[lane] = removed_words[c * CWORDS + lane] | ~valid_words[c * CWORDS + lane];
    __syncthreads();

    for (int s = 0; s < CWORDS; ++s) {
        int r = (c << 11) + s * 64 + lane;    // own row
        const ulonglong2* rowp = (const ulonglong2*)(diag + (size_t)r * CWORDS);
        u64 own[CWORDS];
#pragma unroll
        for (int p = 0; p < 16; ++p) {
            ulonglong2 v; v.x = 0; v.y = 0;
            if (2 * p + 1 >= s) v = rowp[p];
            own[2 * p] = v.x; own[2 * p + 1] = v.y;
        }
        __syncthreads();   // prior iteration's LDS atomics visible
        u64 W = state[s];
        u64 own_s = 0;
#pragma unroll
        for (int w = 0; w < CWORDS; ++w) own_s = (w == s) ? own[w] : own_s;

        u64 alive = ~W;
        u64 kept = 0;
        while (alive) {
            int t = __ffsll(alive) - 1;     // uniform across wave
            kept |= 1ull << t;
            u64 dw = __shfl(own_s, t);      // row t's same-word suppressions (bits > t only)
            alive &= ~dw;
            alive &= (t == 63) ? 0ull : (~0ull << (t + 1));
        }
        if (lane == 0) kept_words[c * CWORDS + s] = kept;

        bool me_kept = (kept >> lane) & 1ull;
#pragma unroll
        for (int w = 0; w < CWORDS; ++w) {
            if (w > s) {
                if (me_kept && own[w]) atomicOr(&state[w], own[w]);
            }
        }
    }
}

// ---------------- apply chunk's kept boxes to all later candidates ----------------
__global__ void elim_kernel(const float4* __restrict__ sboxes, const float* __restrict__ sarea,
                            const u64* __restrict__ kept_words, u64* __restrict__ removed_words,
                            int c) {
    __shared__ float4 kb[CHUNK];
    __shared__ float ka[CHUNK];
    __shared__ int cnt;
    int tid = threadIdx.x;
    if (tid == 0) cnt = 0;
    __syncthreads();
    int cb = c << 11;
    for (int li = tid; li < CHUNK; li += 256) {
        if ((kept_words[c * CWORDS + (li >> 6)] >> (li & 63)) & 1ull) {
            int k = atomicAdd(&cnt, 1);
            kb[k] = sboxes[cb + li];
            ka[k] = sarea[cb + li];
        }
    }
    __syncthreads();
    int f = ((c + 1) << 11) + blockIdx.x * 256 + tid;
    if (f < N_ANCH) {
        float4 bf = sboxes[f];
        float af = sarea[f];
        bool sup = false;
        int n = cnt;
        for (int k = 0; k < n; ++k) {
            sup = sup || iou_gt(kb[k], ka[k], bf, af);
        }
        if (sup) atomicOr(&removed_words[f >> 6], 1ull << (f & 63));
    }
}

// ---------------- output ----------------
__global__ void output_kernel(const float4* __restrict__ boxes, const float* __restrict__ score,
                              const int* __restrict__ rank, const u64* __restrict__ kept_words,
                              float* __restrict__ out) {
    int i = blockIdx.x * 256 + threadIdx.x;
    if (i >= N_ANCH) return;
    int p = rank[i];
    float m = ((kept_words[p >> 6] >> (p & 63)) & 1ull) ? 1.0f : 0.0f;
    float4 b = boxes[i];
    float s = score[i];
    out[(size_t)i * 5 + 0] = __fmul_rn(b.x, m);
    out[(size_t)i * 5 + 1] = __fmul_rn(b.y, m);
    out[(size_t)i * 5 + 2] = __fmul_rn(b.z, m);
    out[(size_t)i * 5 + 3] = __fmul_rn(b.w, m);
    out[(size_t)i * 5 + 4] = __fmul_rn(s, m);
}

extern "C" void kernel_launch(void* const* d_in, const int* in_sizes, int n_in,
                              void* d_out, int out_size, void* d_ws, size_t ws_size,
                              hipStream_t stream) {
    const float4* loc = (const float4*)d_in[0];
    const float* cls = (const float*)d_in[1];
    char* ws = (char*)d_ws;

    float4* boxes      = (float4*)(ws + 0);        // 196608
    float*  score      = (float*)(ws + 196608);    // 49152
    u32*    key        = (u32*)  (ws + 245760);    // 49152
    float*  area       = (float*)(ws + 294912);    // 49152
    int*    rank       = (int*)  (ws + 344064);    // 49152
    float4* sboxes     = (float4*)(ws + 393216);   // 196608
    float*  sarea      = (float*)(ws + 589824);    // 49152
    u64*    valid_w    = (u64*)  (ws + 638976);    // 1536
    u64*    removed_w  = (u64*)  (ws + 640512);    // 1536
    u64*    kept_w     = (u64*)  (ws + 642048);    // 1536
    u64*    diag       = (u64*)  (ws + 643584);    // 3145728  (total ~3.62 MB)

    hipMemsetAsync(valid_w, 0, 3 * 1536, stream);

    decode_kernel<<<48, 256, 0, stream>>>(loc, cls, boxes, score, key, area);
    rank_kernel<<<384, 256, 0, stream>>>(key, boxes, area, score, rank, sboxes, sarea, valid_w);
    diag_kernel<<<N_ANCH, 256, 0, stream>>>(sboxes, sarea, diag);

    for (int c = 0; c < NCHUNK; ++c) {
        scan_kernel<<<1, 64, 0, stream>>>(diag, valid_w, removed_w, kept_w, c);
        if (c < NCHUNK - 1) {
            int start = (c + 1) * CHUNK;
            int cntf = N_ANCH - start;
            elim_kernel<<<(cntf + 255) / 256, 256, 0, stream>>>(sboxes, sarea, kept_w, removed_w, c);
        }
    }

    output_kernel<<<48, 256, 0, stream>>>(boxes, score, rank, kept_w, (float*)d_out);
}

// Round 2
// 342.012 us; speedup vs baseline: 7.5761x; 7.5761x over previous
//
#include <hip/hip_runtime.h>
#include <stdint.h>

#define N_ANCH 12288
#define FM_W 128
#define NCLS 64
#define CHUNK 2048
#define NCHUNK 6
#define CWORDS 32
#define TOTWORDS 192

typedef unsigned long long u64;
typedef unsigned int u32;

// IoU > 0.5 predicate, replicating numpy op order/rounding exactly (no FMA contraction).
__device__ __forceinline__ bool iou_gt(float4 a, float fa, float4 b, float fb) {
    float xx1 = fmaxf(a.x, b.x);
    float yy1 = fmaxf(a.y, b.y);
    float xx2 = fminf(a.z, b.z);
    float yy2 = fminf(a.w, b.w);
    float dx = fmaxf(__fsub_rn(xx2, xx1), 0.0f);
    float dy = fmaxf(__fsub_rn(yy2, yy1), 0.0f);
    float inter = __fmul_rn(dx, dy);
    float denom = __fadd_rn(__fsub_rn(__fadd_rn(fa, fb), inter), 1e-9f);
    float iou = __fdiv_rn(inter, denom);
    return iou > 0.5f;
}

// ---------------- decode: boxes, score, sortable key, area ----------------
__global__ void decode_kernel(const float4* __restrict__ loc, const float* __restrict__ cls,
                              float4* __restrict__ boxes, float* __restrict__ score,
                              u32* __restrict__ key, float* __restrict__ area) {
    int i = blockIdx.x * 256 + threadIdx.x;
    if (i >= N_ANCH) return;
    float4 l = loc[i];
    int y = i >> 7;        // FM_W = 128
    int x = i & 127;
    float cx = (x + 0.5f) * 8.0f;   // exact
    float cy = (y + 0.5f) * 8.0f;   // exact
    float px = __fadd_rn(__fmul_rn(l.x, 32.0f), cx);
    float py = __fadd_rn(__fmul_rn(l.y, 32.0f), cy);
    float pw = __fmul_rn(expf(l.z), 32.0f);
    float ph = __fmul_rn(expf(l.w), 32.0f);
    float hx = __fmul_rn(pw, 0.5f);
    float hy = __fmul_rn(ph, 0.5f);
    float x1 = __fsub_rn(px, hx), y1 = __fsub_rn(py, hy);
    float x2 = __fadd_rn(px, hx), y2 = __fadd_rn(py, hy);
    float4 b; b.x = x1; b.y = y1; b.z = x2; b.w = y2;
    boxes[i] = b;
    area[i] = __fmul_rn(__fsub_rn(x2, x1), __fsub_rn(y2, y1));

    const float4* cr = (const float4*)(cls + (size_t)i * NCLS);
    float mx = -INFINITY;
#pragma unroll
    for (int k = 0; k < 16; ++k) {
        float4 v = cr[k];
        mx = fmaxf(mx, fmaxf(fmaxf(v.x, v.y), fmaxf(v.z, v.w)));
    }
    float s;
    if (mx >= 0.0f) {
        float e = expf(-mx);
        s = __fdiv_rn(1.0f, __fadd_rn(1.0f, e));
    } else {
        float e = expf(mx);
        s = __fdiv_rn(e, __fadd_rn(1.0f, e));
    }
    score[i] = s;
    float se = (s > 0.5f) ? s : -INFINITY;   // score_eff
    u32 u = __float_as_uint(se);
    u = (u & 0x80000000u) ? ~u : (u | 0x80000000u);   // ascending-ordered uint
    key[i] = u;
}

// ---------------- rank sort: stable descending argsort via O(N^2) rank ----------------
__global__ void rank_kernel(const u32* __restrict__ key, const float4* __restrict__ boxes,
                            const float* __restrict__ area, const float* __restrict__ score,
                            int* __restrict__ rank, float4* __restrict__ sboxes,
                            float* __restrict__ sarea, u64* __restrict__ valid_words) {
    __shared__ u32 skey[N_ANCH];
    int tid = threadIdx.x;
    for (int k = tid; k < N_ANCH; k += 256) skey[k] = key[k];
    __syncthreads();
    int row = blockIdx.x * 32 + (tid >> 3);
    int part = tid & 7;
    u32 ki = skey[row];
    int r = 0;
    for (int j = part; j < N_ANCH; j += 8) {
        u32 kj = skey[j];
        r += (int)((kj > ki) || (kj == ki && j < row));
    }
    r += __shfl_xor(r, 1);
    r += __shfl_xor(r, 2);
    r += __shfl_xor(r, 4);
    if (part == 0) {
        rank[row] = r;
        sboxes[r] = boxes[row];
        sarea[r] = area[row];
        if (score[row] > 0.5f) atomicOr(&valid_words[r >> 6], 1ull << (r & 63));
    }
}

// ---------------- per-chunk diagonal suppression mask ----------------
__global__ void diag_kernel(const float4* __restrict__ sboxes, const float* __restrict__ sarea,
                            u64* __restrict__ diag) {
    int i = blockIdx.x;              // global sorted row index
    int c = i >> 11;                 // chunk of 2048
    int lane = threadIdx.x & 63;
    int wave = threadIdx.x >> 6;     // 0..3
    float4 bi = sboxes[i];
    float ai = sarea[i];
    int cb = c << 11;
#pragma unroll
    for (int w8 = 0; w8 < 8; ++w8) {
        int w = wave * 8 + w8;
        int j = cb + w * 64 + lane;
        float4 bj = sboxes[j];
        float aj = sarea[j];
        bool pred = iou_gt(bi, ai, bj, aj) && (j > i);
        u64 bits = __ballot(pred);
        if (lane == 0) diag[(size_t)i * CWORDS + w] = bits;
    }
}

// ---------------- sequential greedy scan within one chunk (1 wave) ----------------
__global__ void scan_kernel(const u64* __restrict__ diag, const u64* __restrict__ valid_words,
                            const u64* __restrict__ removed_words, u64* __restrict__ kept_words,
                            int c) {
    __shared__ u64 state[CWORDS];
    int lane = threadIdx.x;
    if (lane < CWORDS)
        state[lane] = removed_words[c * CWORDS + lane] | ~valid_words[c * CWORDS + lane];

    u64 own[CWORDS];
    u64 nxt[CWORDS];
    // preload step-0 rows
    {
        const ulonglong2* rp = (const ulonglong2*)(diag + (size_t)((c << 11) + lane) * CWORDS);
#pragma unroll
        for (int p = 0; p < 16; ++p) { ulonglong2 v = rp[p]; own[2 * p] = v.x; own[2 * p + 1] = v.y; }
    }

#pragma unroll
    for (int s = 0; s < CWORDS; ++s) {
        __syncthreads();   // prior iteration's LDS atomics visible; drains loads issued one iter ago
        // prefetch next step's rows (latency hides under the walk below)
        if (s + 1 < CWORDS) {
            const ulonglong2* rp = (const ulonglong2*)(diag + (size_t)((c << 11) + (s + 1) * 64 + lane) * CWORDS);
#pragma unroll
            for (int p = 0; p < 16; ++p) { ulonglong2 v = rp[p]; nxt[2 * p] = v.x; nxt[2 * p + 1] = v.y; }
        }
        u64 W = state[s];
        u64 own_s = own[s];              // static index (loop fully unrolled)
        u64 suppmask = __ballot(own_s != 0ull);   // lanes that suppress someone in this word
        u64 cur = ~W;
        u64 kept = 0;
        // walk only suppressor lanes; everyone alive before the first suppressor is kept in bulk
        while (true) {
            u64 m = cur & suppmask;
            if (m == 0) { kept |= cur; break; }
            int t = __ffsll(m) - 1;
            u64 below = (t == 0) ? 0ull : (cur & ((1ull << t) - 1ull));
            kept |= below | (1ull << t);
            u32 lo = __builtin_amdgcn_readlane((u32)own_s, t);
            u32 hi = __builtin_amdgcn_readlane((u32)(own_s >> 32), t);
            u64 dw = ((u64)hi << 32) | (u64)lo;
            cur &= ~dw;
            cur &= (t == 63) ? 0ull : (~0ull << (t + 1));
        }
        if (lane == 0) kept_words[c * CWORDS + s] = kept;

        bool me_kept = (kept >> lane) & 1ull;
#pragma unroll
        for (int w = 0; w < CWORDS; ++w) {
            if (w > s) {
                if (me_kept && own[w]) atomicOr(&state[w], own[w]);
            }
        }
#pragma unroll
        for (int w = 0; w < CWORDS; ++w) own[w] = nxt[w];
    }
}

// ---------------- apply chunk's kept boxes to all later candidates ----------------
// grid: (future-groups of 256) x (8 slices of 256 chunk entries)
__global__ void elim_kernel(const float4* __restrict__ sboxes, const float* __restrict__ sarea,
                            const u64* __restrict__ kept_words, u64* __restrict__ removed_words,
                            int c) {
    __shared__ float4 kb[256];
    __shared__ float ka[256];
    __shared__ u64 kw[4];
    int tid = threadIdx.x;
    int cb = c << 11;
    int sb = cb + blockIdx.y * 256;
    kb[tid] = sboxes[sb + tid];
    ka[tid] = sarea[sb + tid];
    if (tid < 4) kw[tid] = kept_words[c * CWORDS + blockIdx.y * 4 + tid];
    __syncthreads();
    int f = ((c + 1) << 11) + blockIdx.x * 256 + tid;
    bool inb = f < N_ANCH;
    float4 bf;
    float af;
    if (inb) { bf = sboxes[f]; af = sarea[f]; }
    else     { bf = make_float4(0.f, 0.f, 0.f, 0.f); af = 0.f; }
    bool sup = false;
#pragma unroll 8
    for (int k = 0; k < 256; ++k) {
        bool kept = (kw[k >> 6] >> (k & 63)) & 1ull;
        sup |= (kept & iou_gt(kb[k], ka[k], bf, af));
    }
    if (sup && inb) atomicOr(&removed_words[f >> 6], 1ull << (f & 63));
}

// ---------------- output ----------------
__global__ void output_kernel(const float4* __restrict__ boxes, const float* __restrict__ score,
                              const int* __restrict__ rank, const u64* __restrict__ kept_words,
                              float* __restrict__ out) {
    int i = blockIdx.x * 256 + threadIdx.x;
    if (i >= N_ANCH) return;
    int p = rank[i];
    float m = ((kept_words[p >> 6] >> (p & 63)) & 1ull) ? 1.0f : 0.0f;
    float4 b = boxes[i];
    float s = score[i];
    out[(size_t)i * 5 + 0] = __fmul_rn(b.x, m);
    out[(size_t)i * 5 + 1] = __fmul_rn(b.y, m);
    out[(size_t)i * 5 + 2] = __fmul_rn(b.z, m);
    out[(size_t)i * 5 + 3] = __fmul_rn(b.w, m);
    out[(size_t)i * 5 + 4] = __fmul_rn(s, m);
}

extern "C" void kernel_launch(void* const* d_in, const int* in_sizes, int n_in,
                              void* d_out, int out_size, void* d_ws, size_t ws_size,
                              hipStream_t stream) {
    const float4* loc = (const float4*)d_in[0];
    const float* cls = (const float*)d_in[1];
    char* ws = (char*)d_ws;

    float4* boxes      = (float4*)(ws + 0);        // 196608
    float*  score      = (float*)(ws + 196608);    // 49152
    u32*    key        = (u32*)  (ws + 245760);    // 49152
    float*  area       = (float*)(ws + 294912);    // 49152
    int*    rank       = (int*)  (ws + 344064);    // 49152
    float4* sboxes     = (float4*)(ws + 393216);   // 196608
    float*  sarea      = (float*)(ws + 589824);    // 49152
    u64*    valid_w    = (u64*)  (ws + 638976);    // 1536
    u64*    removed_w  = (u64*)  (ws + 640512);    // 1536
    u64*    kept_w     = (u64*)  (ws + 642048);    // 1536
    u64*    diag       = (u64*)  (ws + 643584);    // 3145728  (total ~3.62 MB)

    hipMemsetAsync(valid_w, 0, 3 * 1536, stream);

    decode_kernel<<<48, 256, 0, stream>>>(loc, cls, boxes, score, key, area);
    rank_kernel<<<384, 256, 0, stream>>>(key, boxes, area, score, rank, sboxes, sarea, valid_w);
    diag_kernel<<<N_ANCH, 256, 0, stream>>>(sboxes, sarea, diag);

    for (int c = 0; c < NCHUNK; ++c) {
        scan_kernel<<<1, 64, 0, stream>>>(diag, valid_w, removed_w, kept_w, c);
        if (c < NCHUNK - 1) {
            int start = (c + 1) * CHUNK;
            int cntf = N_ANCH - start;
            dim3 g((cntf + 255) / 256, 8);
            elim_kernel<<<g, 256, 0, stream>>>(sboxes, sarea, kept_w, removed_w, c);
        }
    }

    output_kernel<<<48, 256, 0, stream>>>(boxes, score, rank, kept_w, (float*)d_out);
}

// Round 3
// 322.726 us; speedup vs baseline: 8.0289x; 1.0598x over previous
//
#include <hip/hip_runtime.h>
#include <stdint.h>

#define N_ANCH 12288
#define NCLS 64
#define CHUNK 2048
#define NCHUNK 6
#define CWORDS 32

typedef unsigned long long u64;
typedef unsigned int u32;

// IoU > 0.5 predicate, replicating numpy op order/rounding exactly (no FMA contraction).
__device__ __forceinline__ bool iou_gt(float4 a, float fa, float4 b, float fb) {
    float xx1 = fmaxf(a.x, b.x);
    float yy1 = fmaxf(a.y, b.y);
    float xx2 = fminf(a.z, b.z);
    float yy2 = fminf(a.w, b.w);
    float dx = fmaxf(__fsub_rn(xx2, xx1), 0.0f);
    float dy = fmaxf(__fsub_rn(yy2, yy1), 0.0f);
    float inter = __fmul_rn(dx, dy);
    float denom = __fadd_rn(__fsub_rn(__fadd_rn(fa, fb), inter), 1e-9f);
    float iou = __fdiv_rn(inter, denom);
    return iou > 0.5f;
}

// ---------------- decode: boxes, score, sortable key, area (+ zero bit arrays) ----------------
__global__ void decode_kernel(const float4* __restrict__ loc, const float* __restrict__ cls,
                              float4* __restrict__ boxes, float* __restrict__ score,
                              u32* __restrict__ key, float* __restrict__ area,
                              u64* __restrict__ zero_base) {
    int i = blockIdx.x * 256 + threadIdx.x;
    if (blockIdx.x == 0) {
        for (int k = threadIdx.x; k < 3 * 192; k += 256) zero_base[k] = 0ull;  // valid/removed/kept
    }
    if (i >= N_ANCH) return;
    float4 l = loc[i];
    int y = i >> 7;        // FM_W = 128
    int x = i & 127;
    float cx = (x + 0.5f) * 8.0f;   // exact
    float cy = (y + 0.5f) * 8.0f;   // exact
    float px = __fadd_rn(__fmul_rn(l.x, 32.0f), cx);
    float py = __fadd_rn(__fmul_rn(l.y, 32.0f), cy);
    float pw = __fmul_rn(expf(l.z), 32.0f);
    float ph = __fmul_rn(expf(l.w), 32.0f);
    float hx = __fmul_rn(pw, 0.5f);
    float hy = __fmul_rn(ph, 0.5f);
    float x1 = __fsub_rn(px, hx), y1 = __fsub_rn(py, hy);
    float x2 = __fadd_rn(px, hx), y2 = __fadd_rn(py, hy);
    float4 b; b.x = x1; b.y = y1; b.z = x2; b.w = y2;
    boxes[i] = b;
    area[i] = __fmul_rn(__fsub_rn(x2, x1), __fsub_rn(y2, y1));

    const float4* cr = (const float4*)(cls + (size_t)i * NCLS);
    float mx = -INFINITY;
#pragma unroll
    for (int k = 0; k < 16; ++k) {
        float4 v = cr[k];
        mx = fmaxf(mx, fmaxf(fmaxf(v.x, v.y), fmaxf(v.z, v.w)));
    }
    float s;
    if (mx >= 0.0f) {
        float e = expf(-mx);
        s = __fdiv_rn(1.0f, __fadd_rn(1.0f, e));
    } else {
        float e = expf(mx);
        s = __fdiv_rn(e, __fadd_rn(1.0f, e));
    }
    score[i] = s;
    float se = (s > 0.5f) ? s : -INFINITY;   // score_eff
    u32 u = __float_as_uint(se);
    u = (u & 0x80000000u) ? ~u : (u | 0x80000000u);   // ascending-ordered uint
    key[i] = u;
}

// ---------------- rank sort: stable descending argsort via O(N^2) rank ----------------
// 768 blocks x 256 threads; 16 rows/block, 16 parts/row; uint4 LDS reads.
__global__ void rank_kernel(const u32* __restrict__ key, const float4* __restrict__ boxes,
                            const float* __restrict__ area, const float* __restrict__ score,
                            int* __restrict__ rank, float4* __restrict__ sboxes,
                            float* __restrict__ sarea, u64* __restrict__ valid_words) {
    __shared__ u32 skey[N_ANCH];
    int tid = threadIdx.x;
    {
        uint4* s4 = (uint4*)skey;
        const uint4* g4 = (const uint4*)key;
        for (int k = tid; k < N_ANCH / 4; k += 256) s4[k] = g4[k];
    }
    __syncthreads();
    int part = tid & 15;
    int row = blockIdx.x * 16 + (tid >> 4);
    u32 ki = skey[row];
    int r = 0;
    // j = k*64 + part*4 + e : strided, 2-way-bank b128 reads (free), 4-row broadcast
    for (int k = 0; k < N_ANCH / 64; ++k) {
        int j0 = (k << 6) + (part << 2);
        uint4 v = *(const uint4*)&skey[j0];
        r += (int)(v.x > ki) + (int)((v.x == ki) && (j0 + 0 < row));
        r += (int)(v.y > ki) + (int)((v.y == ki) && (j0 + 1 < row));
        r += (int)(v.z > ki) + (int)((v.z == ki) && (j0 + 2 < row));
        r += (int)(v.w > ki) + (int)((v.w == ki) && (j0 + 3 < row));
    }
    r += __shfl_xor(r, 1);
    r += __shfl_xor(r, 2);
    r += __shfl_xor(r, 4);
    r += __shfl_xor(r, 8);
    if (part == 0) {
        rank[row] = r;
        sboxes[r] = boxes[row];
        sarea[r] = area[row];
        if (score[row] > 0.5f) atomicOr(&valid_words[r >> 6], 1ull << (r & 63));
    }
}

// ---------------- per-chunk diagonal suppression mask ----------------
__global__ void diag_kernel(const float4* __restrict__ sboxes, const float* __restrict__ sarea,
                            u64* __restrict__ diag) {
    int i = blockIdx.x;              // global sorted row index
    int c = i >> 11;                 // chunk of 2048
    int lane = threadIdx.x & 63;
    int wave = threadIdx.x >> 6;     // 0..3
    float4 bi = sboxes[i];
    float ai = sarea[i];
    int cb = c << 11;
#pragma unroll
    for (int w8 = 0; w8 < 8; ++w8) {
        int w = wave * 8 + w8;
        int j = cb + w * 64 + lane;
        float4 bj = sboxes[j];
        float aj = sarea[j];
        bool pred = iou_gt(bi, ai, bj, aj) && (j > i);
        u64 bits = __ballot(pred);
        if (lane == 0) diag[(size_t)i * CWORDS + w] = bits;
    }
}

// ---------------- sequential greedy scan within one chunk (1 wave) ----------------
// 3-deep register-ring prefetch: loads for step S+3 issued at step S.
#define LOADROW(S, B) do { \
    const ulonglong2* rp_ = (const ulonglong2*)(diag + (size_t)(cb + (S) * 64 + lane) * CWORDS); \
    _Pragma("unroll") \
    for (int p_ = 0; p_ < 16; ++p_) { ulonglong2 v_ = rp_[p_]; B[2 * p_] = v_.x; B[2 * p_ + 1] = v_.y; } \
} while (0)

#define STEP(S, B) do { \
    __syncthreads(); \
    u64 W_ = state[S]; \
    u64 own_s_ = B[S]; \
    u64 suppmask_ = __ballot(own_s_ != 0ull); \
    u64 cur_ = ~W_; \
    u64 kept_ = 0; \
    while (true) { \
        u64 m_ = cur_ & suppmask_; \
        if (m_ == 0) { kept_ |= cur_; break; } \
        int t_ = __ffsll(m_) - 1; \
        u64 below_ = (t_ == 0) ? 0ull : (cur_ & ((1ull << t_) - 1ull)); \
        kept_ |= below_ | (1ull << t_); \
        u32 lo_ = __builtin_amdgcn_readlane((u32)own_s_, t_); \
        u32 hi_ = __builtin_amdgcn_readlane((u32)(own_s_ >> 32), t_); \
        u64 dw_ = ((u64)hi_ << 32) | (u64)lo_; \
        cur_ &= ~dw_; \
        cur_ &= (t_ == 63) ? 0ull : (~0ull << (t_ + 1)); \
    } \
    if (lane == 0) kept_words[c * CWORDS + (S)] = kept_; \
    { \
        bool me_ = (kept_ >> lane) & 1ull; \
        _Pragma("unroll") \
        for (int w_ = 0; w_ < CWORDS; ++w_) { \
            if (w_ > (S)) { if (me_ && B[w_]) atomicOr(&state[w_], B[w_]); } \
        } \
    } \
    if ((S) + 3 < CWORDS) LOADROW((S) + 3, B); \
} while (0)

__global__ void __launch_bounds__(64, 1)
scan_kernel(const u64* __restrict__ diag, const u64* __restrict__ valid_words,
            const u64* __restrict__ removed_words, u64* __restrict__ kept_words,
            int c) {
    __shared__ u64 state[CWORDS];
    int lane = threadIdx.x;
    if (lane < CWORDS)
        state[lane] = removed_words[c * CWORDS + lane] | ~valid_words[c * CWORDS + lane];
    int cb = c << 11;

    u64 b0[CWORDS], b1[CWORDS], b2[CWORDS];
    LOADROW(0, b0); LOADROW(1, b1); LOADROW(2, b2);

    STEP(0, b0);  STEP(1, b1);  STEP(2, b2);
    STEP(3, b0);  STEP(4, b1);  STEP(5, b2);
    STEP(6, b0);  STEP(7, b1);  STEP(8, b2);
    STEP(9, b0);  STEP(10, b1); STEP(11, b2);
    STEP(12, b0); STEP(13, b1); STEP(14, b2);
    STEP(15, b0); STEP(16, b1); STEP(17, b2);
    STEP(18, b0); STEP(19, b1); STEP(20, b2);
    STEP(21, b0); STEP(22, b1); STEP(23, b2);
    STEP(24, b0); STEP(25, b1); STEP(26, b2);
    STEP(27, b0); STEP(28, b1); STEP(29, b2);
    STEP(30, b0); STEP(31, b1);
}

// ---------------- apply chunk's kept boxes to all later candidates ----------------
// grid: (future-groups of 256) x (8 slices of 256 chunk entries)
__global__ void elim_kernel(const float4* __restrict__ sboxes, const float* __restrict__ sarea,
                            const u64* __restrict__ kept_words, u64* __restrict__ removed_words,
                            int c) {
    __shared__ float4 kb[256];
    __shared__ float ka[256];
    __shared__ u64 kw[4];
    int tid = threadIdx.x;
    int cb = c << 11;
    int sb = cb + blockIdx.y * 256;
    kb[tid] = sboxes[sb + tid];
    ka[tid] = sarea[sb + tid];
    if (tid < 4) kw[tid] = kept_words[c * CWORDS + blockIdx.y * 4 + tid];
    __syncthreads();
    int f = ((c + 1) << 11) + blockIdx.x * 256 + tid;
    bool inb = f < N_ANCH;
    float4 bf;
    float af;
    if (inb) { bf = sboxes[f]; af = sarea[f]; }
    else     { bf = make_float4(0.f, 0.f, 0.f, 0.f); af = 0.f; }
    bool sup = false;
#pragma unroll 8
    for (int k = 0; k < 256; ++k) {
        bool kept = (kw[k >> 6] >> (k & 63)) & 1ull;
        sup |= (kept & iou_gt(kb[k], ka[k], bf, af));
    }
    if (sup && inb) atomicOr(&removed_words[f >> 6], 1ull << (f & 63));
}

// ---------------- output ----------------
__global__ void output_kernel(const float4* __restrict__ boxes, const float* __restrict__ score,
                              const int* __restrict__ rank, const u64* __restrict__ kept_words,
                              float* __restrict__ out) {
    int i = blockIdx.x * 256 + threadIdx.x;
    if (i >= N_ANCH) return;
    int p = rank[i];
    float m = ((kept_words[p >> 6] >> (p & 63)) & 1ull) ? 1.0f : 0.0f;
    float4 b = boxes[i];
    float s = score[i];
    out[(size_t)i * 5 + 0] = __fmul_rn(b.x, m);
    out[(size_t)i * 5 + 1] = __fmul_rn(b.y, m);
    out[(size_t)i * 5 + 2] = __fmul_rn(b.z, m);
    out[(size_t)i * 5 + 3] = __fmul_rn(b.w, m);
    out[(size_t)i * 5 + 4] = __fmul_rn(s, m);
}

extern "C" void kernel_launch(void* const* d_in, const int* in_sizes, int n_in,
                              void* d_out, int out_size, void* d_ws, size_t ws_size,
                              hipStream_t stream) {
    const float4* loc = (const float4*)d_in[0];
    const float* cls = (const float*)d_in[1];
    char* ws = (char*)d_ws;

    float4* boxes      = (float4*)(ws + 0);        // 196608
    float*  score      = (float*)(ws + 196608);    // 49152
    u32*    key        = (u32*)  (ws + 245760);    // 49152
    float*  area       = (float*)(ws + 294912);    // 49152
    int*    rank       = (int*)  (ws + 344064);    // 49152
    float4* sboxes     = (float4*)(ws + 393216);   // 196608
    float*  sarea      = (float*)(ws + 589824);    // 49152
    u64*    valid_w    = (u64*)  (ws + 638976);    // 1536
    u64*    removed_w  = (u64*)  (ws + 640512);    // 1536
    u64*    kept_w     = (u64*)  (ws + 642048);    // 1536
    u64*    diag       = (u64*)  (ws + 643584);    // 3145728

    decode_kernel<<<48, 256, 0, stream>>>(loc, cls, boxes, score, key, area, valid_w);
    rank_kernel<<<768, 256, 0, stream>>>(key, boxes, area, score, rank, sboxes, sarea, valid_w);
    diag_kernel<<<N_ANCH, 256, 0, stream>>>(sboxes, sarea, diag);

    for (int c = 0; c < NCHUNK; ++c) {
        scan_kernel<<<1, 64, 0, stream>>>(diag, valid_w, removed_w, kept_w, c);
        if (c < NCHUNK - 1) {
            int start = (c + 1) * CHUNK;
            int cntf = N_ANCH - start;
            dim3 g((cntf + 255) / 256, 8);
            elim_kernel<<<g, 256, 0, stream>>>(sboxes, sarea, kept_w, removed_w, c);
        }
    }

    output_kernel<<<48, 256, 0, stream>>>(boxes, score, rank, kept_w, (float*)d_out);
}